// Round 10
// baseline (141.953 us; speedup 1.0000x reference)
//
#include <hip/hip_runtime.h>
#include <hip/hip_bf16.h>
#include <math.h>

#define T_    100
#define D_    50
#define H_    30
#define HALF  5120
#define EMB_  20
#define NEMB_ 10
#define OUT_  10

typedef _Float16 h2    __attribute__((ext_vector_type(2)));
typedef _Float16 f16x8 __attribute__((ext_vector_type(8)));
typedef float    f32x4 __attribute__((ext_vector_type(4)));

union FR  { f16x8 v; h2 p[4]; float4 f4; };

__device__ __forceinline__ h2 pk(float a, float b) {
    return __builtin_bit_cast(h2, __builtin_amdgcn_cvt_pkrtz(a, b));
}
__device__ __forceinline__ int pki(float a, float b) {
    return __builtin_bit_cast(int, __builtin_amdgcn_cvt_pkrtz(a, b));
}

#define EXP2(x) exp2f(x)

// Prefetch buffer: 16 VGPRs, pinned live by asm-volatile loads.
struct B4 { float4 A0, A1, B0, B1; };

// ---------------------------------------------------------------------------
// GRU: 1 wave per block, 16 sequences per wave. 640 blocks.
// Swapped MFMA: C[g][s] = Wext[g][k] * Hext[s][k]; gate rows g = gate*32 + j
// so lane (s = l&15, q = l>>4) holds the (r,z,n) triple for j = 16u + 4q + r.
// h in registers; B-frag rebuilt per step with 8 bpermute + selects.
// Round 10 (= round 9 with the tied-operand compile error fixed): x prefetch
// via inline-asm global_load_dwordx4 (depth 4, 16 loads in flight) + counted
// "s_waitcnt vmcnt(12)" (untied, "memory" clobber) + sched_barrier(0) per
// guide rule #18 to stop the scheduler hoisting dependent code above the
// wait. Compiler can't sink/drop asm-volatile loads or widen the wait.
// Biases fold into MFMA: Hext[30]=1.0 (constant p3) -> b_hh; x[50]=1 -> b_ih.
// log2e folded into staged weights so gates use raw v_exp_f32.
// ---------------------------------------------------------------------------
__global__ __launch_bounds__(64, 1) void gru_kernel(
    const float* __restrict__ input1, const float* __restrict__ input2,
    const float* __restrict__ W_ih,  const float* __restrict__ W_hh,
    const float* __restrict__ b_ih,  const float* __restrict__ b_hh,
    float* __restrict__ emb1_out,    // [5120][30]
    float* __restrict__ h2_out)      // [5120][30]
{
    const int lane = threadIdx.x & 63;
    const int s    = lane & 15;
    const int q    = lane >> 4;
    const int n    = blockIdx.x * 16 + s;

    __shared__ __align__(16) _Float16 Wst [96 * 64];  // W_ih ext (12 KB)
    __shared__ __align__(16) _Float16 Whst[96 * 32];  // W_hh ext (6 KB)

    const float SC_RZ = -1.4426950408889634f;   // -log2(e)
    const float SC_N  =  2.8853900817779268f;   // +2*log2(e)

    for (int i = lane; i < 1536; i += 64) ((unsigned long long*)Wst)[i]  = 0ull;
    for (int i = lane; i < 768;  i += 64) ((unsigned long long*)Whst)[i] = 0ull;

    for (int i = 0; i < 71; ++i) {
        int idx = lane + i * 64;
        if (idx < 4500) {
            int rw = idx / 50, k = idx - rw * 50;
            int g  = rw / 30;
            int ge = rw + 2 * g;
            float sc = (g < 2) ? SC_RZ : SC_N;
            Wst[ge * 64 + k] = (_Float16)(W_ih[idx] * sc);
        }
    }
    for (int i = 0; i < 2; ++i) {
        int idx = lane + i * 64;
        if (idx < 90) {
            int g = idx / 30; int ge = idx + 2 * g;
            float sc = (g < 2) ? SC_RZ : SC_N;
            Wst[ge * 64 + 50] = (_Float16)(b_ih[idx] * sc);
        }
    }
    for (int i = 0; i < 43; ++i) {
        int idx = lane + i * 64;
        if (idx < 2700) {
            int rw = idx / 30, k = idx - rw * 30;
            int g  = rw / 30;
            int ge = rw + 2 * g;
            float sc = (g < 2) ? SC_RZ : SC_N;
            Whst[ge * 32 + k] = (_Float16)(W_hh[idx] * sc);
        }
    }
    for (int i = 0; i < 2; ++i) {
        int idx = lane + i * 64;
        if (idx < 90) {
            int g = idx / 30; int ge = idx + 2 * g;
            float sc = (g < 2) ? SC_RZ : SC_N;
            Whst[ge * 32 + 30] = (_Float16)(b_hh[idx] * sc);
        }
    }
    __syncthreads();

    FR wih[6][2], whh[6];
    #pragma unroll
    for (int nt = 0; nt < 6; ++nt) {
        wih[nt][0].f4 = *(const float4*)&Wst [(nt * 16 + s) * 64 + q * 8];
        wih[nt][1].f4 = *(const float4*)&Wst [(nt * 16 + s) * 64 + 32 + q * 8];
        whh[nt].f4    = *(const float4*)&Whst[(nt * 16 + s) * 32 + q * 8];
    }

    const float* xp = (n < HALF) ? input1 + (size_t)n * (T_ * D_)
                                 : input2 + (size_t)(n - HALF) * (T_ * D_);

    // per-lane fixed float offsets within a row
    const int aoff = q * 8;                       // floats q*8..q*8+7
    const int boff = (q < 2) ? (32 + q * 8) : 42; // q<2: 32..47; q>=2: 42..49

    // ---- asm-pinned load: 4 x global_load_dwordx4, offset-folded ----
    auto issue_load = [&](int t, B4& b) {
        const float* pa = xp + t * D_ + aoff;
        const float* pb = xp + t * D_ + boff;
        asm volatile("global_load_dwordx4 %0, %1, off"           : "=v"(b.A0) : "v"(pa));
        asm volatile("global_load_dwordx4 %0, %1, off offset:16" : "=v"(b.A1) : "v"(pa));
        asm volatile("global_load_dwordx4 %0, %1, off"           : "=v"(b.B0) : "v"(pb));
        asm volatile("global_load_dwordx4 %0, %1, off offset:16" : "=v"(b.B1) : "v"(pb));
    };
    // counted wait: oldest buffer (4 loads) complete. Untied; sched_barrier
    // keeps dependent builds below the wait (guide rule #18).
    auto wait_buf = [&]() {
        asm volatile("s_waitcnt vmcnt(12)" ::: "memory");
        __builtin_amdgcn_sched_barrier(0);
    };

    auto build = [&](const B4& X, FR& x0, FR& x1) {
        x0.p[0] = pk(X.A0.x, X.A0.y); x0.p[1] = pk(X.A0.z, X.A0.w);
        x0.p[2] = pk(X.A1.x, X.A1.y); x0.p[3] = pk(X.A1.z, X.A1.w);
        if (q < 2) {
            x1.p[0] = pk(X.B0.x, X.B0.y); x1.p[1] = pk(X.B0.z, X.B0.w);
            x1.p[2] = pk(X.B1.x, X.B1.y); x1.p[3] = pk(X.B1.z, X.B1.w);
        } else if (q == 2) {
            // boff=42: B1 = floats 46..49 -> (48,49) = (z,w); col 50 = bias 1
            x1.p[0] = pk(X.B1.z, X.B1.w); x1.p[1] = pk(1.f, 0.f);
            x1.p[2] = pk(0.f, 0.f);       x1.p[3] = pk(0.f, 0.f);
        } else {
            x1.p[0] = pk(0.f, 0.f); x1.p[1] = pk(0.f, 0.f);
            x1.p[2] = pk(0.f, 0.f); x1.p[3] = pk(0.f, 0.f);
        }
    };

    float hold[8] = {0.f, 0.f, 0.f, 0.f, 0.f, 0.f, 0.f, 0.f};
    int w0 = 0, w1 = 0, w2 = 0, w3 = 0;
    const int la = ((2 * q) & 3) * 16 + s;
    const int lb = ((2 * q + 1) & 3) * 16 + s;
    const int ONE = pki(1.f, 0.f);

    auto step = [&](const FR& x0, const FR& x1) {
        const int A0 = __shfl(w0, la), A1 = __shfl(w1, la);
        const int A2 = __shfl(w2, la), A3 = __shfl(w3, la);
        const int B0 = __shfl(w0, lb), B1 = __shfl(w1, lb);
        const int B2 = __shfl(w2, lb), B3 = __shfl(w3, lb);
        FR bh;
        bh.p[0] = __builtin_bit_cast(h2, q < 2 ? A0 : A2);
        bh.p[1] = __builtin_bit_cast(h2, q < 2 ? A1 : A3);
        bh.p[2] = __builtin_bit_cast(h2, q < 2 ? B0 : B2);
        bh.p[3] = __builtin_bit_cast(h2, q == 3 ? ONE : (q < 2 ? B1 : B3));

        f32x4 arz[4], anh[2], anx[2];
        #pragma unroll
        for (int nt = 0; nt < 4; ++nt) {
            f32x4 acc = {0.f, 0.f, 0.f, 0.f};
            acc = __builtin_amdgcn_mfma_f32_16x16x32_f16(wih[nt][0].v, x0.v, acc, 0, 0, 0);
            acc = __builtin_amdgcn_mfma_f32_16x16x32_f16(wih[nt][1].v, x1.v, acc, 0, 0, 0);
            acc = __builtin_amdgcn_mfma_f32_16x16x32_f16(whh[nt].v,    bh.v, acc, 0, 0, 0);
            arz[nt] = acc;
        }
        #pragma unroll
        for (int u = 0; u < 2; ++u) {
            f32x4 ax = {0.f, 0.f, 0.f, 0.f}, ah = {0.f, 0.f, 0.f, 0.f};
            ax = __builtin_amdgcn_mfma_f32_16x16x32_f16(wih[4 + u][0].v, x0.v, ax, 0, 0, 0);
            ax = __builtin_amdgcn_mfma_f32_16x16x32_f16(wih[4 + u][1].v, x1.v, ax, 0, 0, 0);
            ah = __builtin_amdgcn_mfma_f32_16x16x32_f16(whh[4 + u].v,    bh.v, ah, 0, 0, 0);
            anh[u] = ah; anx[u] = ax;
        }
        #pragma unroll
        for (int u = 0; u < 2; ++u) {
            #pragma unroll
            for (int r = 0; r < 4; ++r) {
                const float rg = __builtin_amdgcn_rcpf(1.f + EXP2(arz[u][r]));
                const float zg = __builtin_amdgcn_rcpf(1.f + EXP2(arz[2 + u][r]));
                const float aa = fmaf(rg, anh[u][r], anx[u][r]);
                const float th = fmaf(-2.f, __builtin_amdgcn_rcpf(1.f + EXP2(aa)), 1.f);
                hold[u * 4 + r] = fmaf(zg, hold[u * 4 + r] - th, th);
            }
        }
        w0 = pki(hold[0], hold[1]); w1 = pki(hold[2], hold[3]);
        w2 = pki(hold[4], hold[5]); w3 = pki(hold[6], hold[7]);
    };

    // ---- depth-4 pinned pipeline: 16 loads in flight, vmcnt(12) waits ----
    B4 Bf0, Bf1, Bf2, Bf3;
    issue_load(0, Bf0); issue_load(1, Bf1);
    issue_load(2, Bf2); issue_load(3, Bf3);
    #pragma unroll 1
    for (int k = 0; k < 25; ++k) {
        const int t = 4 * k;
        FR x0, x1;
        int tn;
        wait_buf(); build(Bf0, x0, x1);
        tn = t + 4; tn = tn > 99 ? 99 : tn; issue_load(tn, Bf0); step(x0, x1);
        wait_buf(); build(Bf1, x0, x1);
        tn = t + 5; tn = tn > 99 ? 99 : tn; issue_load(tn, Bf1); step(x0, x1);
        wait_buf(); build(Bf2, x0, x1);
        tn = t + 6; tn = tn > 99 ? 99 : tn; issue_load(tn, Bf2); step(x0, x1);
        wait_buf(); build(Bf3, x0, x1);
        tn = t + 7; tn = tn > 99 ? 99 : tn; issue_load(tn, Bf3); step(x0, x1);
    }
    asm volatile("s_waitcnt vmcnt(0)" ::: "memory");   // drain before endpgm

    float* outp = (n < HALF) ? emb1_out + (size_t)n * H_
                             : h2_out + (size_t)(n - HALF) * H_;
    #pragma unroll
    for (int u = 0; u < 2; ++u)
        #pragma unroll
        for (int r = 0; r < 4; ++r) {
            const int j = 16 * u + 4 * q + r;
            if (j < H_) outp[j] = hold[u * 4 + r];
        }
}

// ---------------------------------------------------------------------------
__global__ __launch_bounds__(64) void mlp_kernel(
    const float* __restrict__ h2i,
    const float* __restrict__ W1, const float* __restrict__ b1,
    const float* __restrict__ W2, const float* __restrict__ b2,
    const float* __restrict__ W3, const float* __restrict__ b3,
    float* __restrict__ logit)
{
    const int b    = blockIdx.x;
    const int lane = threadIdx.x;
    __shared__ float e2[300];
    const float* row = h2i + (size_t)b * 300;
    #pragma unroll
    for (int i = lane; i < 75; i += 64)
        *(float4*)&e2[i * 4] = *(const float4*)(row + i * 4);
    __syncthreads();

    const float kInvSqrt2 = 0.70710678118654752f;
    float y1 = 0.f;
    if (lane < EMB_) {
        float acc = b1[lane];
        const float* wp = W1 + lane * 300;
        #pragma unroll
        for (int qq = 0; qq < 75; ++qq) {
            float4 wv = *(const float4*)(wp + qq * 4);
            acc += wv.x * e2[qq*4 + 0] + wv.y * e2[qq*4 + 1]
                 + wv.z * e2[qq*4 + 2] + wv.w * e2[qq*4 + 3];
        }
        y1 = 0.5f * acc * (1.f + erff(acc * kInvSqrt2));
    }
    float acc2 = (lane < NEMB_) ? b2[lane] : 0.f;
    #pragma unroll
    for (int e = 0; e < EMB_; ++e) {
        const float v = __shfl(y1, e);
        if (lane < NEMB_) acc2 += v * W2[lane * EMB_ + e];
    }
    const float y2 = 0.5f * acc2 * (1.f + erff(acc2 * kInvSqrt2));
    float acc3 = (lane < OUT_) ? b3[lane] : 0.f;
    #pragma unroll
    for (int e = 0; e < NEMB_; ++e) {
        const float v = __shfl(y2, e);
        if (lane < OUT_) acc3 += v * W3[lane * NEMB_ + e];
    }
    if (lane < OUT_) logit[(size_t)b * OUT_ + lane] = acc3;
}

// ---------------------------------------------------------------------------
extern "C" void kernel_launch(void* const* d_in, const int* in_sizes, int n_in,
                              void* d_out, int out_size, void* d_ws, size_t ws_size,
                              hipStream_t stream) {
    const float* input1 = (const float*)d_in[0];
    const float* input2 = (const float*)d_in[1];
    const float* W_ih   = (const float*)d_in[2];
    const float* W_hh   = (const float*)d_in[3];
    const float* b_ih   = (const float*)d_in[4];
    const float* b_hh   = (const float*)d_in[5];
    const float* W1     = (const float*)d_in[6];
    const float* b1     = (const float*)d_in[7];
    const float* W2     = (const float*)d_in[8];
    const float* b2     = (const float*)d_in[9];
    const float* W3     = (const float*)d_in[10];
    const float* b3     = (const float*)d_in[11];

    float* out = (float*)d_out;
    float* h2s = (float*)d_ws;

    hipLaunchKernelGGL(gru_kernel, dim3(640), dim3(64), 0, stream,
                       input1, input2, W_ih, W_hh, b_ih, b_hh,
                       out + 5120, h2s);
    hipLaunchKernelGGL(mlp_kernel, dim3(512), dim3(64), 0, stream,
                       h2s, W1, b1, W2, b2, W3, b3, out);
}